// Round 1
// baseline (200.577 us; speedup 1.0000x reference)
//
#include <hip/hip_runtime.h>
#include <hip/hip_bf16.h>

// Problem constants
#define BATCH 32
#define CIN   64
#define COUT  64
#define HIN   58
#define WIN   58
#define HOUT  56
#define WOUT  56
#define RSIZE 512
#define NB    10
#define EDIM  64
#define HID   128

// ---------------- Kernel A: routing -> softmax weights ----------------
__global__ __launch_bounds__(128) void routing_kernel(
    const float* __restrict__ rv, const float* __restrict__ W1,
    const float* __restrict__ b1, const float* __restrict__ W2,
    const float* __restrict__ b2, const float* __restrict__ emb,
    float* __restrict__ weights_out)
{
    const int b = blockIdx.x;
    const int t = threadIdx.x;
    __shared__ float s_rv[RSIZE];
    __shared__ float s_h[HID];
    __shared__ float s_r[EDIM];
    __shared__ float s_rnorm;
    __shared__ float s_sim[16];

    for (int i = t; i < RSIZE; i += 128) s_rv[i] = rv[b * RSIZE + i];
    __syncthreads();

    // hidden = relu(rv @ W1 + b1), W1 is [512,128]
    {
        float acc = b1[t];
        for (int k = 0; k < RSIZE; ++k) acc = fmaf(s_rv[k], W1[k * HID + t], acc);
        s_h[t] = fmaxf(acc, 0.0f);
    }
    __syncthreads();

    // r = h @ W2 + b2, W2 is [128,64]
    if (t < EDIM) {
        float acc = b2[t];
        for (int j = 0; j < HID; ++j) acc = fmaf(s_h[j], W2[j * EDIM + t], acc);
        s_r[t] = acc;
        float sq = acc * acc;
        #pragma unroll
        for (int off = 32; off > 0; off >>= 1) sq += __shfl_xor(sq, off);
        if (t == 0) s_rnorm = sqrtf(sq);
    }
    __syncthreads();

    // cosine sim vs each embedding
    if (t < NB) {
        float dot = 0.0f, nb2 = 0.0f;
        for (int e = 0; e < EDIM; ++e) {
            float ev = emb[t * EDIM + e];
            dot = fmaf(ev, s_r[e], dot);
            nb2 = fmaf(ev, ev, nb2);
        }
        s_sim[t] = dot / ((s_rnorm + 1e-8f) * (sqrtf(nb2) + 1e-8f));
    }
    __syncthreads();

    if (t == 0) {
        float m = -1e30f;
        #pragma unroll
        for (int n = 0; n < NB; ++n) m = fmaxf(m, s_sim[n]);
        float w[NB];
        float sum = 0.0f;
        #pragma unroll
        for (int n = 0; n < NB; ++n) { w[n] = __expf(s_sim[n] - m); sum += w[n]; }
        float inv = 1.0f / sum;
        float d = 0.0f;
        #pragma unroll
        for (int n = 0; n < NB; ++n) { w[n] *= inv; d += w[n]; }
        float invd = 1.0f / d;
        #pragma unroll
        for (int n = 0; n < NB; ++n) weights_out[b * NB + n] = w[n] * invd;
    }
}

// ---------------- Kernel B: mixed-expert 3x3 valid conv ----------------
// grid = BATCH * (COUT/4) = 512 blocks, 256 threads.
// Block (b, cog): computes out[b, 4*cog .. 4*cog+3, :, :].
// LDS: x chunk of 4 cin channels [4][58*58], mixed weights wl[cin][kh][co][kw(pad4)].
#define NTILES 784   // 56 rows * 14 four-wide ow tiles

__global__ __launch_bounds__(256, 2) void conv_mix_kernel(
    const float* __restrict__ x, const float* __restrict__ conv_w,
    const float* __restrict__ conv_b, const float* __restrict__ weights,
    float* __restrict__ out)
{
    const int blk = blockIdx.x;
    const int b   = blk >> 4;
    const int cog = blk & 15;
    const int co0 = cog * 4;
    const int t   = threadIdx.x;

    __shared__ float xs[4 * HIN * WIN];        // 53824 B
    __shared__ float wl[CIN * 3 * 4 * 4];      // 12288 B, [cin][kh][co][kw pad 4]
    __shared__ float sbias[4];
    __shared__ float sw[NB];

    if (t < NB) sw[t] = weights[b * NB + t];
    __syncthreads();

    // Mix expert conv weights for this block's 4 output channels.
    for (int idx = t; idx < CIN * 3 * 4 * 4; idx += 256) {
        const int kw  = idx & 3;
        const int co  = (idx >> 2) & 3;
        const int kh  = (idx >> 4) % 3;
        const int cin = idx / 48;
        float v = 0.0f;
        if (kw < 3) {
            const int base = (co0 + co) * (CIN * 9) + cin * 9 + kh * 3 + kw;
            #pragma unroll
            for (int n = 0; n < NB; ++n)
                v = fmaf(sw[n], conv_w[n * (COUT * CIN * 9) + base], v);
        }
        wl[idx] = v;
    }
    if (t < 4) {
        float v = 0.0f;
        #pragma unroll
        for (int n = 0; n < NB; ++n) v = fmaf(sw[n], conv_b[n * COUT + co0 + t], v);
        sbias[t] = v;
    }

    // Per-thread tiles: tile = t + 256*i, tile < 784. oh = tile/14, owb = (tile%14)*4.
    int   xoff[4];
    bool  tval[4];
    #pragma unroll
    for (int i = 0; i < 4; ++i) {
        const int tile = t + 256 * i;
        tval[i] = (tile < NTILES);
        const int oh  = tile / 14;
        const int owb = (tile - oh * 14) * 4;
        xoff[i] = oh * WIN + owb;
    }

    float acc[4][4][4];
    #pragma unroll
    for (int i = 0; i < 4; ++i)
        #pragma unroll
        for (int co = 0; co < 4; ++co)
            #pragma unroll
            for (int q = 0; q < 4; ++q) acc[i][co][q] = 0.0f;

    const float4* xg4 = (const float4*)(x + (size_t)(b * CIN) * (HIN * WIN));
    float4* xs4 = (float4*)xs;
    const int ch_f4 = (HIN * WIN) / 4;   // 841 float4 per channel

    for (int cc = 0; cc < CIN / 4; ++cc) {
        __syncthreads();   // protect xs against previous iteration's readers
        // stage 4 channels: 4*841 = 3364 float4
        const int base_f4 = cc * 4 * ch_f4;
        for (int idx = t; idx < 4 * ch_f4; idx += 256)
            xs4[idx] = xg4[base_f4 + idx];
        __syncthreads();

        #pragma unroll
        for (int c = 0; c < 4; ++c) {
            #pragma unroll
            for (int kh = 0; kh < 3; ++kh) {
                // hoist the 12 mixed weights for (cin, kh) into registers
                float wv[4][3];
                const int wbase = (cc * 4 + c) * 48 + kh * 16;
                #pragma unroll
                for (int co = 0; co < 4; ++co)
                    #pragma unroll
                    for (int kw = 0; kw < 3; ++kw)
                        wv[co][kw] = wl[wbase + co * 4 + kw];

                #pragma unroll
                for (int i = 0; i < 4; ++i) {
                    if (tval[i]) {
                        const float* xp = &xs[c * (HIN * WIN) + xoff[i] + kh * WIN];
                        const float x0 = xp[0], x1 = xp[1], x2 = xp[2];
                        const float x3 = xp[3], x4 = xp[4], x5 = xp[5];
                        #pragma unroll
                        for (int co = 0; co < 4; ++co) {
                            acc[i][co][0] = fmaf(x2, wv[co][2], fmaf(x1, wv[co][1], fmaf(x0, wv[co][0], acc[i][co][0])));
                            acc[i][co][1] = fmaf(x3, wv[co][2], fmaf(x2, wv[co][1], fmaf(x1, wv[co][0], acc[i][co][1])));
                            acc[i][co][2] = fmaf(x4, wv[co][2], fmaf(x3, wv[co][1], fmaf(x2, wv[co][0], acc[i][co][2])));
                            acc[i][co][3] = fmaf(x5, wv[co][2], fmaf(x4, wv[co][1], fmaf(x3, wv[co][0], acc[i][co][3])));
                        }
                    }
                }
            }
        }
    }

    // Epilogue: add bias, store float4.
    #pragma unroll
    for (int i = 0; i < 4; ++i) {
        if (tval[i]) {
            const int tile = t + 256 * i;
            const int oh  = tile / 14;
            const int owb = (tile - oh * 14) * 4;
            #pragma unroll
            for (int co = 0; co < 4; ++co) {
                const float bia = sbias[co];
                float4 v;
                v.x = acc[i][co][0] + bia;
                v.y = acc[i][co][1] + bia;
                v.z = acc[i][co][2] + bia;
                v.w = acc[i][co][3] + bia;
                *(float4*)&out[(((size_t)(b * COUT + co0 + co) * HOUT + oh) * WOUT) + owb] = v;
            }
        }
    }
}

extern "C" void kernel_launch(void* const* d_in, const int* in_sizes, int n_in,
                              void* d_out, int out_size, void* d_ws, size_t ws_size,
                              hipStream_t stream) {
    const float* x    = (const float*)d_in[0];
    const float* rv   = (const float*)d_in[1];
    const float* W1   = (const float*)d_in[2];
    const float* b1   = (const float*)d_in[3];
    const float* W2   = (const float*)d_in[4];
    const float* b2   = (const float*)d_in[5];
    const float* emb  = (const float*)d_in[6];
    const float* cw   = (const float*)d_in[7];
    const float* cb   = (const float*)d_in[8];
    float* out = (float*)d_out;
    float* wts = (float*)d_ws;   // 32*10 floats

    routing_kernel<<<dim3(BATCH), dim3(128), 0, stream>>>(rv, W1, b1, W2, b2, emb, wts);
    conv_mix_kernel<<<dim3(BATCH * (COUT / 4)), dim3(256), 0, stream>>>(x, cw, cb, wts, out);
}

// Round 2
// 176.525 us; speedup vs baseline: 1.1362x; 1.1362x over previous
//
#include <hip/hip_runtime.h>
#include <hip/hip_bf16.h>
#include <stdint.h>

// Problem constants
#define BATCH 32
#define CIN   64
#define COUT  64
#define HIN   58
#define WIN   58
#define HOUT  56
#define WOUT  56
#define RSIZE 512
#define NB    10
#define EDIM  64
#define HID   128

#define CHW        (HIN*WIN)          // 3364
#define WEFF_PER_BLK (CIN*4*9)        // 2304 floats per (b,cog)
#define WEFF_TOTAL (BATCH*16*WEFF_PER_BLK)  // 1,179,648 floats

__device__ __forceinline__ const float* uniform_ptr(const float* p){
    uint64_t u = (uint64_t)(uintptr_t)p;
    uint32_t lo = __builtin_amdgcn_readfirstlane((uint32_t)u);
    uint32_t hi = __builtin_amdgcn_readfirstlane((uint32_t)(u >> 32));
    return (const float*)(uintptr_t)(((uint64_t)hi << 32) | lo);
}

// ---------------- Kernel A: routing -> softmax weights ----------------
__global__ __launch_bounds__(128) void routing_kernel(
    const float* __restrict__ rv, const float* __restrict__ W1,
    const float* __restrict__ b1, const float* __restrict__ W2,
    const float* __restrict__ b2, const float* __restrict__ emb,
    float* __restrict__ weights_out)
{
    const int b = blockIdx.x;
    const int t = threadIdx.x;
    __shared__ float s_rv[RSIZE];
    __shared__ float s_h[HID];
    __shared__ float s_r[EDIM];
    __shared__ float s_rnorm;
    __shared__ float s_sim[16];

    for (int i = t; i < RSIZE; i += 128) s_rv[i] = rv[b * RSIZE + i];
    __syncthreads();

    {
        float acc = b1[t];
        for (int k = 0; k < RSIZE; ++k) acc = fmaf(s_rv[k], W1[k * HID + t], acc);
        s_h[t] = fmaxf(acc, 0.0f);
    }
    __syncthreads();

    if (t < EDIM) {
        float acc = b2[t];
        for (int j = 0; j < HID; ++j) acc = fmaf(s_h[j], W2[j * EDIM + t], acc);
        s_r[t] = acc;
        float sq = acc * acc;
        #pragma unroll
        for (int off = 32; off > 0; off >>= 1) sq += __shfl_xor(sq, off);
        if (t == 0) s_rnorm = sqrtf(sq);
    }
    __syncthreads();

    if (t < NB) {
        float dot = 0.0f, nb2 = 0.0f;
        for (int e = 0; e < EDIM; ++e) {
            float ev = emb[t * EDIM + e];
            dot = fmaf(ev, s_r[e], dot);
            nb2 = fmaf(ev, ev, nb2);
        }
        s_sim[t] = dot / ((s_rnorm + 1e-8f) * (sqrtf(nb2) + 1e-8f));
    }
    __syncthreads();

    if (t == 0) {
        float m = -1e30f;
        #pragma unroll
        for (int n = 0; n < NB; ++n) m = fmaxf(m, s_sim[n]);
        float w[NB];
        float sum = 0.0f;
        #pragma unroll
        for (int n = 0; n < NB; ++n) { w[n] = __expf(s_sim[n] - m); sum += w[n]; }
        float inv = 1.0f / sum;
        float d = 0.0f;
        #pragma unroll
        for (int n = 0; n < NB; ++n) { w[n] *= inv; d += w[n]; }
        float invd = 1.0f / d;
        #pragma unroll
        for (int n = 0; n < NB; ++n) weights_out[b * NB + n] = w[n] * invd;
    }
}

// ---------------- Kernel B0: mix expert weights into w_eff ----------------
// w_eff layout: [b][cog][cin][co4][3][3]  (36 contiguous floats per (blk,cin))
__global__ __launch_bounds__(256) void wmix_kernel(
    const float* __restrict__ cw, const float* __restrict__ wts,
    float* __restrict__ weff)
{
    const int blk = blockIdx.x;          // b*16 + cog
    const int b   = blk >> 4;
    const int cog = blk & 15;
    __shared__ float sw[NB];
    if (threadIdx.x < NB) sw[threadIdx.x] = wts[b * NB + threadIdx.x];
    __syncthreads();
    for (int e = threadIdx.x; e < WEFF_PER_BLK; e += 256) {
        const int cin = e / 36;
        const int rem = e - cin * 36;
        const int co  = rem / 9;
        const int k   = rem - co * 9;
        const float* src = cw + (((size_t)(cog * 4 + co) * CIN + cin) * 9 + k);
        float v = 0.0f;
        #pragma unroll
        for (int n = 0; n < NB; ++n)
            v = fmaf(sw[n], src[(size_t)n * (COUT * CIN * 9)], v);
        weff[(size_t)blk * WEFF_PER_BLK + e] = v;
    }
}

// ---------------- Kernel B1: conv with SGPR weights ----------------
// grid = 512 blocks (b,cog), 512 threads. Thread tile: 2oh x 2ow x 4cout.
// 784 2x2 spatial tiles per block; thread t handles tiles t and t+512.
__global__ __launch_bounds__(512, 4) void conv2_kernel(
    const float* __restrict__ x, const float* __restrict__ weff,
    const float* __restrict__ conv_b, const float* __restrict__ wts,
    float* __restrict__ out)
{
    const int blk = blockIdx.x;
    const int b   = blk >> 4;
    const int cog = blk & 15;
    const int co0 = cog * 4;
    const int t   = threadIdx.x;

    __shared__ float xs[4 * CHW];      // 53824 B
    __shared__ float sbias[4];

    if (t < 4) {
        float v = 0.0f;
        #pragma unroll
        for (int n = 0; n < NB; ++n)
            v = fmaf(wts[b * NB + n], conv_b[n * COUT + co0 + t], v);
        sbias[t] = v;
    }

    int  xbase[2], obase[2];
    bool tval[2];
    #pragma unroll
    for (int i = 0; i < 2; ++i) {
        const int tile = t + 512 * i;
        tval[i] = (tile < 784);
        const int oh2 = tile / 28;
        const int ow2 = tile - oh2 * 28;
        xbase[i] = (2 * oh2) * WIN + 2 * ow2;
        obase[i] = (2 * oh2) * WOUT + 2 * ow2;
    }

    float acc[2][4][2][2];
    #pragma unroll
    for (int i = 0; i < 2; ++i)
        #pragma unroll
        for (int co = 0; co < 4; ++co)
            #pragma unroll
            for (int qh = 0; qh < 2; ++qh)
                #pragma unroll
                for (int qw = 0; qw < 2; ++qw) acc[i][co][qh][qw] = 0.0f;

    const float* xg   = x + (size_t)b * CIN * CHW;
    const float* wblk = weff + (size_t)blk * WEFF_PER_BLK;

    for (int cc = 0; cc < 16; ++cc) {
        __syncthreads();   // previous chunk's readers done
        // stage channels 4cc..4cc+3 : 3364 float4, linear global->LDS
        const float* src = xg + (size_t)cc * 4 * CHW;
        #pragma unroll
        for (int j = 0; j < 7; ++j) {
            const int idx = t + 512 * j;     // float4 index
            if (idx < CHW) {                 // 3364 float4 per 4-channel chunk
                __builtin_amdgcn_global_load_lds(
                    (const __attribute__((address_space(1))) void*)(src + (size_t)idx * 4),
                    (__attribute__((address_space(3))) void*)(xs + idx * 4),
                    16, 0, 0);
            }
        }
        __syncthreads();   // waitcnt vmcnt(0) + barrier

        #pragma unroll
        for (int c4 = 0; c4 < 4; ++c4) {
            // 36 mixed weights for (cin = 4cc+c4), uniform -> s_load into SGPRs
            const float* wp = uniform_ptr(wblk + (cc * 4 + c4) * 36);
            float w[36];
            #pragma unroll
            for (int j = 0; j < 36; ++j) w[j] = wp[j];

            #pragma unroll
            for (int i = 0; i < 2; ++i) {
                if (!tval[i]) continue;
                float xv[4][4];
                const float* xp = xs + c4 * CHW + xbase[i];
                #pragma unroll
                for (int r = 0; r < 4; ++r) {
                    const float2 a  = *(const float2*)(xp + r * WIN);
                    const float2 bq = *(const float2*)(xp + r * WIN + 2);
                    xv[r][0] = a.x; xv[r][1] = a.y; xv[r][2] = bq.x; xv[r][3] = bq.y;
                }
                #pragma unroll
                for (int co = 0; co < 4; ++co)
                    #pragma unroll
                    for (int kh = 0; kh < 3; ++kh)
                        #pragma unroll
                        for (int kw = 0; kw < 3; ++kw) {
                            const float wv = w[co * 9 + kh * 3 + kw];
                            acc[i][co][0][0] = fmaf(xv[kh    ][kw    ], wv, acc[i][co][0][0]);
                            acc[i][co][0][1] = fmaf(xv[kh    ][kw + 1], wv, acc[i][co][0][1]);
                            acc[i][co][1][0] = fmaf(xv[kh + 1][kw    ], wv, acc[i][co][1][0]);
                            acc[i][co][1][1] = fmaf(xv[kh + 1][kw + 1], wv, acc[i][co][1][1]);
                        }
            }
        }
    }

    #pragma unroll
    for (int i = 0; i < 2; ++i) {
        if (!tval[i]) continue;
        #pragma unroll
        for (int co = 0; co < 4; ++co) {
            const float bia = sbias[co];
            float* op = out + (size_t)(b * COUT + co0 + co) * (HOUT * WOUT) + obase[i];
            #pragma unroll
            for (int qh = 0; qh < 2; ++qh) {
                float2 v;
                v.x = acc[i][co][qh][0] + bia;
                v.y = acc[i][co][qh][1] + bia;
                *(float2*)(op + qh * WOUT) = v;
            }
        }
    }
}

// ---------------- Fallback conv (round-1, LDS weights) ----------------
#define NTILES 784

__global__ __launch_bounds__(256, 2) void conv_mix_kernel(
    const float* __restrict__ x, const float* __restrict__ conv_w,
    const float* __restrict__ conv_b, const float* __restrict__ weights,
    float* __restrict__ out)
{
    const int blk = blockIdx.x;
    const int b   = blk >> 4;
    const int cog = blk & 15;
    const int co0 = cog * 4;
    const int t   = threadIdx.x;

    __shared__ float xs[4 * HIN * WIN];
    __shared__ float wl[CIN * 3 * 4 * 4];
    __shared__ float sbias[4];
    __shared__ float sw[NB];

    if (t < NB) sw[t] = weights[b * NB + t];
    __syncthreads();

    for (int idx = t; idx < CIN * 3 * 4 * 4; idx += 256) {
        const int kw  = idx & 3;
        const int co  = (idx >> 2) & 3;
        const int kh  = (idx >> 4) % 3;
        const int cin = idx / 48;
        float v = 0.0f;
        if (kw < 3) {
            const int base = (co0 + co) * (CIN * 9) + cin * 9 + kh * 3 + kw;
            #pragma unroll
            for (int n = 0; n < NB; ++n)
                v = fmaf(sw[n], conv_w[n * (COUT * CIN * 9) + base], v);
        }
        wl[idx] = v;
    }
    if (t < 4) {
        float v = 0.0f;
        #pragma unroll
        for (int n = 0; n < NB; ++n) v = fmaf(sw[n], conv_b[n * COUT + co0 + t], v);
        sbias[t] = v;
    }

    int   xoff[4];
    bool  tval[4];
    #pragma unroll
    for (int i = 0; i < 4; ++i) {
        const int tile = t + 256 * i;
        tval[i] = (tile < NTILES);
        const int oh  = tile / 14;
        const int owb = (tile - oh * 14) * 4;
        xoff[i] = oh * WIN + owb;
    }

    float acc[4][4][4];
    #pragma unroll
    for (int i = 0; i < 4; ++i)
        #pragma unroll
        for (int co = 0; co < 4; ++co)
            #pragma unroll
            for (int q = 0; q < 4; ++q) acc[i][co][q] = 0.0f;

    const float4* xg4 = (const float4*)(x + (size_t)(b * CIN) * (HIN * WIN));
    float4* xs4 = (float4*)xs;
    const int ch_f4 = (HIN * WIN) / 4;

    for (int cc = 0; cc < CIN / 4; ++cc) {
        __syncthreads();
        const int base_f4 = cc * 4 * ch_f4;
        for (int idx = t; idx < 4 * ch_f4; idx += 256)
            xs4[idx] = xg4[base_f4 + idx];
        __syncthreads();

        #pragma unroll
        for (int c = 0; c < 4; ++c) {
            #pragma unroll
            for (int kh = 0; kh < 3; ++kh) {
                float wv[4][3];
                const int wbase = (cc * 4 + c) * 48 + kh * 16;
                #pragma unroll
                for (int co = 0; co < 4; ++co)
                    #pragma unroll
                    for (int kw = 0; kw < 3; ++kw)
                        wv[co][kw] = wl[wbase + co * 4 + kw];

                #pragma unroll
                for (int i = 0; i < 4; ++i) {
                    if (tval[i]) {
                        const float* xp = &xs[c * (HIN * WIN) + xoff[i] + kh * WIN];
                        const float x0 = xp[0], x1 = xp[1], x2 = xp[2];
                        const float x3 = xp[3], x4 = xp[4], x5 = xp[5];
                        #pragma unroll
                        for (int co = 0; co < 4; ++co) {
                            acc[i][co][0] = fmaf(x2, wv[co][2], fmaf(x1, wv[co][1], fmaf(x0, wv[co][0], acc[i][co][0])));
                            acc[i][co][1] = fmaf(x3, wv[co][2], fmaf(x2, wv[co][1], fmaf(x1, wv[co][0], acc[i][co][1])));
                            acc[i][co][2] = fmaf(x4, wv[co][2], fmaf(x3, wv[co][1], fmaf(x2, wv[co][0], acc[i][co][2])));
                            acc[i][co][3] = fmaf(x5, wv[co][2], fmaf(x4, wv[co][1], fmaf(x3, wv[co][0], acc[i][co][3])));
                        }
                    }
                }
            }
        }
    }

    #pragma unroll
    for (int i = 0; i < 4; ++i) {
        if (tval[i]) {
            const int tile = t + 256 * i;
            const int oh  = tile / 14;
            const int owb = (tile - oh * 14) * 4;
            #pragma unroll
            for (int co = 0; co < 4; ++co) {
                const float bia = sbias[co];
                float4 v;
                v.x = acc[i][co][0] + bia;
                v.y = acc[i][co][1] + bia;
                v.z = acc[i][co][2] + bia;
                v.w = acc[i][co][3] + bia;
                *(float4*)&out[(((size_t)(b * COUT + co0 + co) * HOUT + oh) * WOUT) + owb] = v;
            }
        }
    }
}

extern "C" void kernel_launch(void* const* d_in, const int* in_sizes, int n_in,
                              void* d_out, int out_size, void* d_ws, size_t ws_size,
                              hipStream_t stream) {
    const float* x    = (const float*)d_in[0];
    const float* rv   = (const float*)d_in[1];
    const float* W1   = (const float*)d_in[2];
    const float* b1   = (const float*)d_in[3];
    const float* W2   = (const float*)d_in[4];
    const float* b2   = (const float*)d_in[5];
    const float* emb  = (const float*)d_in[6];
    const float* cw   = (const float*)d_in[7];
    const float* cb   = (const float*)d_in[8];
    float* out = (float*)d_out;

    float* wts  = (float*)d_ws;            // 320 floats
    float* weff = (float*)d_ws + 1024;     // 1,179,648 floats

    routing_kernel<<<dim3(BATCH), dim3(128), 0, stream>>>(rv, W1, b1, W2, b2, emb, wts);

    const size_t need = (size_t)(1024 + WEFF_TOTAL) * sizeof(float);
    if (ws_size >= need) {
        wmix_kernel<<<dim3(BATCH * 16), dim3(256), 0, stream>>>(cw, wts, weff);
        conv2_kernel<<<dim3(BATCH * 16), dim3(512), 0, stream>>>(x, weff, cb, wts, out);
    } else {
        conv_mix_kernel<<<dim3(BATCH * 16), dim3(256), 0, stream>>>(x, cw, cb, wts, out);
    }
}

// Round 3
// 53.904 us; speedup vs baseline: 3.7210x; 3.2748x over previous
//
#include <hip/hip_runtime.h>
#include <hip/hip_bf16.h>
#include <stdint.h>

// Problem constants
#define BATCH 32
#define CIN   64
#define COUT  64
#define HIN   58
#define WIN   58
#define HOUT  56
#define WOUT  56
#define RSIZE 512
#define NB    10
#define EDIM  64
#define HID   128
#define CHW   (HIN*WIN)     // 3364
#define OHW   (HOUT*WOUT)   // 3136

typedef __attribute__((ext_vector_type(8)))  short short8;
typedef __attribute__((ext_vector_type(16))) float f32x16;

__device__ __forceinline__ unsigned short f2bf(float f) {
    unsigned int u = __builtin_bit_cast(unsigned int, f);
    u += 0x7fffu + ((u >> 16) & 1u);          // RNE
    return (unsigned short)(u >> 16);
}

// ---------------- Kernel A: routing -> softmax weights ----------------
__global__ __launch_bounds__(128) void routing_kernel(
    const float* __restrict__ rv, const float* __restrict__ W1,
    const float* __restrict__ b1, const float* __restrict__ W2,
    const float* __restrict__ b2, const float* __restrict__ emb,
    float* __restrict__ weights_out)
{
    const int b = blockIdx.x;
    const int t = threadIdx.x;
    __shared__ float s_rv[RSIZE];
    __shared__ float s_h[HID];
    __shared__ float s_r[EDIM];
    __shared__ float s_rnorm;
    __shared__ float s_sim[16];

    for (int i = t; i < RSIZE; i += 128) s_rv[i] = rv[b * RSIZE + i];
    __syncthreads();

    {
        float acc = b1[t];
        for (int k = 0; k < RSIZE; ++k) acc = fmaf(s_rv[k], W1[k * HID + t], acc);
        s_h[t] = fmaxf(acc, 0.0f);
    }
    __syncthreads();

    if (t < EDIM) {
        float acc = b2[t];
        for (int j = 0; j < HID; ++j) acc = fmaf(s_h[j], W2[j * EDIM + t], acc);
        s_r[t] = acc;
        float sq = acc * acc;
        #pragma unroll
        for (int off = 32; off > 0; off >>= 1) sq += __shfl_xor(sq, off);
        if (t == 0) s_rnorm = sqrtf(sq);
    }
    __syncthreads();

    if (t < NB) {
        float dot = 0.0f, nb2 = 0.0f;
        for (int e = 0; e < EDIM; ++e) {
            float ev = emb[t * EDIM + e];
            dot = fmaf(ev, s_r[e], dot);
            nb2 = fmaf(ev, ev, nb2);
        }
        s_sim[t] = dot / ((s_rnorm + 1e-8f) * (sqrtf(nb2) + 1e-8f));
    }
    __syncthreads();

    if (t == 0) {
        float m = -1e30f;
        #pragma unroll
        for (int n = 0; n < NB; ++n) m = fmaxf(m, s_sim[n]);
        float w[NB];
        float sum = 0.0f;
        #pragma unroll
        for (int n = 0; n < NB; ++n) { w[n] = __expf(s_sim[n] - m); sum += w[n]; }
        float inv = 1.0f / sum;
        float d = 0.0f;
        #pragma unroll
        for (int n = 0; n < NB; ++n) { w[n] *= inv; d += w[n]; }
        float invd = 1.0f / d;
        #pragma unroll
        for (int n = 0; n < NB; ++n) weights_out[b * NB + n] = w[n] * invd;
    }
}

// ---------------- Kernel B: mix weights -> bf16 [b][co][shift][cin] ----------------
// grid = 256 blocks: co = blk & 63, batch-quad bq = blk >> 6 (8 batches each).
__global__ __launch_bounds__(256) void wmixb_kernel(
    const float* __restrict__ cw, const float* __restrict__ cbias,
    const float* __restrict__ wts,
    unsigned short* __restrict__ weffb, float* __restrict__ sbias_g)
{
    const int co = blockIdx.x & 63;
    const int bq = blockIdx.x >> 6;
    const int t  = threadIdx.x;
    __shared__ float scw[NB * 576];   // cw[n][co][cin][3][3] slice, 23040 B
    __shared__ float sw[8 * NB];

    if (t < 8 * NB) sw[t] = wts[(bq * 8) * NB + t];
    for (int i = t; i < NB * 576; i += 256) {
        const int n = i / 576, rem = i - n * 576;
        scw[i] = cw[(size_t)(n * COUT + co) * 576 + rem];
    }
    __syncthreads();

    for (int i = t; i < 8 * 576; i += 256) {         // 18 iters
        const int bl = i / 576, rem = i - bl * 576;
        const int s = rem >> 6, cin = rem & 63;      // rem = s*64 + cin
        float v = 0.0f;
        #pragma unroll
        for (int n = 0; n < NB; ++n)
            v = fmaf(sw[bl * NB + n], scw[n * 576 + cin * 9 + s], v);
        const int b = bq * 8 + bl;
        weffb[(((size_t)b * COUT + co) * 9 + s) * 64 + cin] = f2bf(v);
    }
    if (t < 8) {
        const int b = bq * 8 + t;
        float v = 0.0f;
        #pragma unroll
        for (int n = 0; n < NB; ++n) v = fmaf(sw[t * NB + n], cbias[n * COUT + co], v);
        sbias_g[b * COUT + co] = v;
    }
}

// ---------------- Kernel C: MFMA implicit-GEMM conv ----------------
// 896 blocks = 32 batches x 28 two-row tiles, XCD-swizzled (896 = 8*112).
// 256 threads = 4 waves: wave = (mt = cout-half, nh = ntile-pair).
// LDS x-tile: [232 sp][40 cin-pad] bf16 (4 input rows x 58 cols, 32-cin chunk).
#define LDSP 40

__global__ __launch_bounds__(256, 2) void conv_mfma_kernel(
    const float* __restrict__ x, const unsigned short* __restrict__ weffb,
    const float* __restrict__ sbias_g, float* __restrict__ out)
{
    const int bid  = blockIdx.x;
    const int xcd  = bid & 7;
    const int slot = bid >> 3;            // 0..111
    const int b    = xcd + 8 * (slot / 28);
    const int tile = slot - (slot / 28) * 28;
    const int oh0  = tile * 2;

    const int t    = threadIdx.x;
    const int wid  = t >> 6;
    const int lane = t & 63;
    const int ln   = lane & 31;           // MFMA n / m within tile
    const int kg   = lane >> 5;           // k-group
    const int mt   = wid & 1;             // cout half: 0 -> co 0..31, 1 -> 32..63
    const int nh   = wid >> 1;            // ntile pair: {2nh, 2nh+1}

    __shared__ unsigned short xs[232 * LDSP];   // 18560 B
    __shared__ float sbias[COUT];

    if (t < COUT) sbias[t] = sbias_g[b * COUT + t];

    // Per-lane B-fragment spatial bases (2 n-tiles of 32 spatial points).
    int boff[2]; int pq[2]; bool val[2];
    #pragma unroll
    for (int nt = 0; nt < 2; ++nt) {
        const int p = (nh * 2 + nt) * 32 + ln;    // 0..127, valid < 112
        val[nt] = (p < 112);
        const int pc = val[nt] ? p : 111;
        pq[nt] = pc;
        const int r = pc / 56, ow = pc - r * 56;
        boff[nt] = (r * WIN + ow) * LDSP + kg * 8;  // element index into xs
    }

    f32x16 acc[2];
    #pragma unroll
    for (int nt = 0; nt < 2; ++nt)
        #pragma unroll
        for (int j = 0; j < 16; ++j) acc[nt][j] = 0.0f;

    const float* xg = x + (size_t)b * CIN * CHW + oh0 * WIN;
    const int wrow = (b * COUT + mt * 32 + ln) * 9;   // A row base (x64 elems)

    for (int cc = 0; cc < 2; ++cc) {
        __syncthreads();    // previous chunk's readers done
        // Stage 32 cins x 232 sp, packed ds_write_b128 (8 cins per thread-item).
        #pragma unroll
        for (int i = 0; i < 4; ++i) {
            const int e = t + 256 * i;       // items: 4 cin-blocks * 232 sp = 928
            if (e < 928) {
                const int cb = e / 232;
                const int sp = e - cb * 232;
                const float* gp = xg + (size_t)(cc * 32 + cb * 8) * CHW + sp;
                short8 v;
                #pragma unroll
                for (int j = 0; j < 8; ++j)
                    v[j] = (short)f2bf(gp[(size_t)j * CHW]);
                *(short8*)&xs[sp * LDSP + cb * 8] = v;
            }
        }
        __syncthreads();

        #pragma unroll
        for (int ks = 0; ks < 2; ++ks) {
            // A fragments: 9 shifts, 16B global loads (L2-resident weffb).
            short8 af[9];
            const unsigned short* wb = weffb + (size_t)wrow * 64 + cc * 32 + ks * 16 + kg * 8;
            #pragma unroll
            for (int s = 0; s < 9; ++s)
                af[s] = *(const short8*)(wb + s * 64);

            #pragma unroll
            for (int s = 0; s < 9; ++s) {
                const int kh = s / 3, kw = s - kh * 3;
                const int soff = (kh * WIN + kw) * LDSP + ks * 16;
                #pragma unroll
                for (int nt = 0; nt < 2; ++nt) {
                    const short8 bf = *(const short8*)&xs[boff[nt] + soff];
                    acc[nt] = __builtin_amdgcn_mfma_f32_32x32x16_bf16(af[s], bf, acc[nt], 0, 0, 0);
                }
            }
        }
    }

    // Epilogue: D row = (reg&3) + 8*(reg>>2) + 4*kg (verified m74/m101), col = ln.
    #pragma unroll
    for (int nt = 0; nt < 2; ++nt) {
        if (!val[nt]) continue;
        const int p = pq[nt];
        const int r = p / 56, ow = p - r * 56;
        float* op = out + ((size_t)(b * COUT + mt * 32) * HOUT + oh0 + r) * WOUT + ow;
        #pragma unroll
        for (int reg = 0; reg < 16; ++reg) {
            const int co_l = (reg & 3) + 8 * (reg >> 2) + 4 * kg;
            op[(size_t)co_l * OHW] = acc[nt][reg] + sbias[mt * 32 + co_l];
        }
    }
}

extern "C" void kernel_launch(void* const* d_in, const int* in_sizes, int n_in,
                              void* d_out, int out_size, void* d_ws, size_t ws_size,
                              hipStream_t stream) {
    const float* x    = (const float*)d_in[0];
    const float* rv   = (const float*)d_in[1];
    const float* W1   = (const float*)d_in[2];
    const float* b1   = (const float*)d_in[3];
    const float* W2   = (const float*)d_in[4];
    const float* b2   = (const float*)d_in[5];
    const float* emb  = (const float*)d_in[6];
    const float* cw   = (const float*)d_in[7];
    const float* cb   = (const float*)d_in[8];
    float* out = (float*)d_out;

    // ws layout: wts [32*10] f32 @0 | sbias [32*64] f32 @1024 | weffb [32*64*9*64] bf16 @3072 floats
    float* wts            = (float*)d_ws;
    float* sbias_g        = (float*)d_ws + 1024;
    unsigned short* weffb = (unsigned short*)((float*)d_ws + 3072);

    routing_kernel<<<dim3(BATCH), dim3(128), 0, stream>>>(rv, W1, b1, W2, b2, emb, wts);
    wmixb_kernel<<<dim3(256), dim3(256), 0, stream>>>(cw, cb, wts, weffb, sbias_g);
    conv_mfma_kernel<<<dim3(BATCH * 28), dim3(256), 0, stream>>>(x, weffb, sbias_g, out);
}